// Round 9
// baseline (466.940 us; speedup 1.0000x reference)
//
#include <hip/hip_runtime.h>
#include <hip/hip_bf16.h>

// Swin window MHSA, MI355X, round 9.
//   k_prep : Aext[2176x256]=G'(+w1/w2 rows), Wov3[256x2048], cvec, relL2(+c0)
//   k_conv : X fp32 -> rolled bf16 Xroll[n][3200][256]
//   k_gemm1: M_T[t][a'] = Xroll . Aext^T  (register-staged, 4 blocks/CU)
//   k_attn4: fused S->softmax->T->Y per (n,window); XOR-swizzled LDS (no bank
//            conflicts) + cross-head register prefetch of M B-frags.

#define NBATCH 8
#define MSTR   2176           // M_T row stride (a'-dim)
#define TROWS  3200           // padded token rows

typedef unsigned short ushort_t;
typedef __attribute__((ext_vector_type(8))) short bf16x8;   // 8 bf16 = 4 VGPR
typedef __attribute__((ext_vector_type(8))) unsigned short u16x8;
typedef __attribute__((ext_vector_type(4))) float f32x4;    // MFMA acc

__device__ __forceinline__ float b2f(ushort_t u) {
  union { unsigned int i; float f; } v; v.i = ((unsigned int)u) << 16; return v.f;
}
__device__ __forceinline__ ushort_t f2b(float f) {
  union { float f; unsigned int u; } v; v.f = f;
  unsigned int u = v.u;
  return (ushort_t)((u + 0x7FFFu + ((u >> 16) & 1u)) >> 16);
}
__device__ __forceinline__ int regof(int y) { return (y < 49) ? 0 : ((y < 53) ? 1 : 2); }
__device__ __forceinline__ int div7(int t) { return (t * 37) >> 8; }  // t/7, t<64
__device__ __forceinline__ int tmap(int p, int gi, int gj) {
  int wi = div7(p); return (gi * 7 + wi) * 56 + gj * 7 + (p - wi * 7);
}
__device__ __forceinline__ ushort4 pack4(f32x4 a) {
  ushort4 u; u.x = f2b(a[0]); u.y = f2b(a[1]); u.z = f2b(a[2]); u.w = f2b(a[3]);
  return u;
}

// ================= prep (unchanged) =================
__global__ void k_prep(const float* __restrict__ Wk, const float* __restrict__ Wq,
                       const float* __restrict__ Wo, const float* __restrict__ Wv,
                       const float* __restrict__ bk, const float* __restrict__ bq,
                       const float* __restrict__ bv, const float* __restrict__ bo,
                       const float* __restrict__ relc,
                       ushort_t* __restrict__ Aext, ushort_t* __restrict__ Wov3,
                       float* __restrict__ cvec, float* __restrict__ relL2) {
  __shared__ float red[8];
  int blk = blockIdx.x, t = threadIdx.x;
  if (blk < 512) {
    int h = blk >> 6, b0 = (blk & 63) << 2, a = t;
    const float* wkh = Wk + h * 65536;
    const float* wqh = Wq + h * 65536;
    float a0 = 0.f, a1 = 0.f, a2 = 0.f, a3 = 0.f;
    for (int dd = 0; dd < 256; ++dd) {
      float wk = wkh[dd * 256 + a];
      float4 w4 = *(const float4*)(wqh + dd * 256 + b0);
      a0 += wk * w4.x; a1 += wk * w4.y; a2 += wk * w4.z; a3 += wk * w4.w;
    }
    ushort4 u; u.x = f2b(a0); u.y = f2b(a1); u.z = f2b(a2); u.w = f2b(a3);
    *(ushort4*)(Aext + (h * 256 + a) * 256 + b0) = u;
  } else if (blk < 1024) {
    int bb = blk - 512;
    int h = bb >> 6, o0 = (bb & 63) << 2, d = t;
    float a0 = 0.f, a1 = 0.f, a2 = 0.f, a3 = 0.f;
    for (int dd = 0; dd < 256; ++dd) {
      float wv = Wv[(h * 256 + dd) * 256 + d];
      a0 += Wo[(o0 + 0) * 2048 + h * 256 + dd] * wv;
      a1 += Wo[(o0 + 1) * 2048 + h * 256 + dd] * wv;
      a2 += Wo[(o0 + 2) * 2048 + h * 256 + dd] * wv;
      a3 += Wo[(o0 + 3) * 2048 + h * 256 + dd] * wv;
    }
    Wov3[(o0 + 0) * 2048 + h * 256 + d] = f2b(a0);
    Wov3[(o0 + 1) * 2048 + h * 256 + d] = f2b(a1);
    Wov3[(o0 + 2) * 2048 + h * 256 + d] = f2b(a2);
    Wov3[(o0 + 3) * 2048 + h * 256 + d] = f2b(a3);
  } else if (blk < 1032) {
    int h = blk - 1024;
    float s1 = 0.f, s2 = 0.f;
    for (int dd = 0; dd < 256; ++dd) {
      s1 += bk[h * 256 + dd] * Wq[(h * 256 + dd) * 256 + t];
      s2 += bq[h * 256 + dd] * Wk[(h * 256 + dd) * 256 + t];
    }
    Aext[(2048 + h) * 256 + t] = f2b(s1);
    Aext[(2056 + h) * 256 + t] = f2b(s2);
  } else if (blk == 1032) {
    for (int i = t; i < 112 * 256 / 8; i += 256)
      *(u16x8*)(Aext + 2064 * 256 + i * 8) = (u16x8){0,0,0,0,0,0,0,0};
  } else if (blk < 1289) {
    int o = blk - 1033;
    const float* wob = Wo + o * 2048;
    float acc = 0.f;
#pragma unroll
    for (int j = 0; j < 8; ++j) acc += wob[j * 256 + t] * bv[j * 256 + t];
#pragma unroll
    for (int s = 1; s < 64; s <<= 1) acc += __shfl_xor(acc, s);
    if ((t & 63) == 0) red[t >> 6] = acc;
    __syncthreads();
    if (t == 0) cvec[o] = bo[o] + red[0] + red[1] + red[2] + red[3];
  } else {
    if (t < 8) {
      float c = 0.f;
      for (int dd = 0; dd < 256; ++dd) c += bk[t * 256 + dd] * bq[t * 256 + dd];
      red[t] = c * 0.0625f;
    }
    __syncthreads();
    for (int i = t; i < 8 * 169; i += 256) {
      int h = i / 169, idx = i - h * 169;
      relL2[i] = relc[idx * 8 + h] + red[h];
    }
  }
}

// ================= conv (unchanged) =================
__global__ void k_conv(const float* __restrict__ X, ushort_t* __restrict__ Xroll) {
  const int n = blockIdx.x / 57, y = blockIdx.x % 57;
  ushort_t* xr = Xroll + (size_t)n * TROWS * 256;
  const int d = threadIdx.x;
  if (y == 56) {
    for (int i = d; i < 64 * 256 / 8; i += 256)
      *(u16x8*)(xr + 3136 * 256 + i * 8) = (u16x8){0,0,0,0,0,0,0,0};
    return;
  }
  const int c = d >> 4, p1 = (d >> 2) & 3, p2 = d & 3;
  const int sp = c * 16 + (((p1 + 1) & 3) << 2) + ((p2 + 1) & 3);
  const int ty = (p1 == 3) ? y : ((y == 0) ? 55 : y - 1);
  const float* rowp = X + (size_t)n * 256 * 3136 + sp * 3136 + ty * 56;
  ushort_t* orow = xr + y * 56 * 256 + d;
  for (int x = 0; x < 56; ++x) {
    int tx = (p2 == 3) ? x : ((x == 0) ? 55 : x - 1);
    orow[x * 256] = f2b(rowp[tx]);
  }
}

// ================= gemm1 (unchanged, occupancy 4) =================
__global__ __launch_bounds__(256, 4) void k_gemm1(
    const ushort_t* __restrict__ Xroll, const ushort_t* __restrict__ Aext,
    ushort_t* __restrict__ MT) {
  __shared__ ushort_t Asm[128 * 72];
  __shared__ ushort_t Bsm[128 * 72];
  const int bx = blockIdx.x;
  const int n = bx / 425, r = bx % 425;
  const int tt = r / 17, aa = r % 17;
  const int a0 = aa * 128, t0 = tt * 128;
  const int tid = threadIdx.x, wave = tid >> 6, lane = tid & 63;
  const int quad = lane >> 4, l16 = lane & 15;
  const int wa = wave >> 1, wt = wave & 1;
  const ushort_t* Xn = Xroll + (size_t)n * TROWS * 256;
  ushort_t* Mn = MT + (size_t)n * TROWS * MSTR;

  const int sr = tid >> 1, sc = (tid & 1) * 4;
  bf16x8 ra[4], rb[4];
#pragma unroll
  for (int i = 0; i < 4; ++i) {
    ra[i] = *(const bf16x8*)(Aext + (a0 + sr) * 256 + (sc + i) * 8);
    rb[i] = *(const bf16x8*)(Xn + (t0 + sr) * 256 + (sc + i) * 8);
  }

  f32x4 acc[4][4];
#pragma unroll
  for (int i = 0; i < 4; ++i)
#pragma unroll
    for (int j = 0; j < 4; ++j) acc[i][j] = (f32x4){0.f, 0.f, 0.f, 0.f};

  for (int kit = 0; kit < 4; ++kit) {
#pragma unroll
    for (int i = 0; i < 4; ++i) {
      *(bf16x8*)(&Asm[sr * 72 + (sc + i) * 8]) = ra[i];
      *(bf16x8*)(&Bsm[sr * 72 + (sc + i) * 8]) = rb[i];
    }
    __syncthreads();
    if (kit < 3) {
      int k0 = (kit + 1) * 64;
#pragma unroll
      for (int i = 0; i < 4; ++i) {
        ra[i] = *(const bf16x8*)(Aext + (a0 + sr) * 256 + k0 + (sc + i) * 8);
        rb[i] = *(const bf16x8*)(Xn + (t0 + sr) * 256 + k0 + (sc + i) * 8);
      }
    }
#pragma unroll
    for (int kk = 0; kk < 2; ++kk) {
      bf16x8 af[4], bf[4];
#pragma unroll
      for (int i = 0; i < 4; ++i)
        af[i] = *(const bf16x8*)(&Asm[(wa * 64 + i * 16 + l16) * 72 + kk * 32 + quad * 8]);
#pragma unroll
      for (int j = 0; j < 4; ++j)
        bf[j] = *(const bf16x8*)(&Bsm[(wt * 64 + j * 16 + l16) * 72 + kk * 32 + quad * 8]);
#pragma unroll
      for (int i = 0; i < 4; ++i)
#pragma unroll
        for (int j = 0; j < 4; ++j)
          acc[i][j] = __builtin_amdgcn_mfma_f32_16x16x32_bf16(af[i], bf[j], acc[i][j], 0, 0, 0);
    }
    __syncthreads();
  }
#pragma unroll
  for (int i = 0; i < 4; ++i)
#pragma unroll
    for (int j = 0; j < 4; ++j) {
      int tg = t0 + wt * 64 + j * 16 + l16;
      int ag = a0 + wa * 64 + i * 16 + quad * 4;
      *(ushort4*)(Mn + (size_t)tg * MSTR + ag) = pack4(acc[i][j]);
    }
}

// ================= attn4: swizzled LDS + cross-head M prefetch =============
// Xp/TT: element (row,d) at row*256 + ((d>>3)^(row&7))*8 + (d&7)   [u16 units]
// StB  : element (q,p)  at q*64  + ((p>>3)^(q&7))*8 + (p&7)
__global__ __launch_bounds__(512, 4) void k_attn4(
    const ushort_t* __restrict__ Xroll, const ushort_t* __restrict__ MT,
    const ushort_t* __restrict__ Wov3, const float* __restrict__ relL2,
    const float* __restrict__ cvec, float* __restrict__ out) {
  __shared__ ushort_t Xp[64 * 256];   // 32 KB
  __shared__ ushort_t TT[64 * 256];   // 32 KB
  __shared__ ushort_t StB[64 * 64];   // 8 KB
  __shared__ float aqsL[8 * 64];
  __shared__ float bpsL[8 * 64];      // total 77.8 KB

  const int tid = threadIdx.x;
  const int wave = tid >> 6, lane = tid & 63;
  const int quad = lane >> 4, l16 = lane & 15;
  const int n = blockIdx.x >> 6, g = blockIdx.x & 63;
  const int gi = g >> 3, gj = g & 7;
  const ushort_t* Xn = Xroll + (size_t)n * TROWS * 256;
  const ushort_t* Mn = MT + (size_t)n * TROWS * MSTR;

  // ---- prologue: Xp gather (swizzled); all-head aq/bp ----
  {
    const int p = tid & 63, cg = tid >> 6;
    if (p < 49) {
      int t = tmap(p, gi, gj);
#pragma unroll
      for (int i = 0; i < 4; ++i) {
        int lc = cg * 4 + i;
        *(u16x8*)(&Xp[p * 256 + ((lc ^ (p & 7)) * 8)]) =
            *(const u16x8*)(Xn + t * 256 + lc * 8);
      }
    } else {
#pragma unroll
      for (int i = 0; i < 4; ++i) {
        int lc = cg * 4 + i;
        *(u16x8*)(&Xp[p * 256 + ((lc ^ (p & 7)) * 8)]) = (u16x8){0,0,0,0,0,0,0,0};
      }
    }
  }
  {
    const int h = tid >> 6, q0 = tid & 63;
    int qq = (q0 < 49) ? q0 : 48;
    int t = tmap(qq, gi, gj);
    aqsL[h * 64 + q0] = b2f(Mn[(size_t)t * MSTR + 2048 + h]);
    bpsL[h * 64 + q0] = b2f(Mn[(size_t)t * MSTR + 2056 + h]);
  }
  __syncthreads();

  // ---- phase-T A-frags: X^T[d][p], d-tiles {2w,2w+1}, in registers ----
  bf16x8 xfr[2][2];
#pragma unroll
  for (int i = 0; i < 2; ++i) {
    const int d = (wave * 2 + i) * 16 + l16;
    const int dc = d >> 3, dof = d & 7;
#pragma unroll
    for (int kk = 0; kk < 2; ++kk)
#pragma unroll
      for (int j = 0; j < 8; ++j) {
        int p = kk * 32 + quad * 8 + j;
        xfr[i][kk][j] = (short)Xp[p * 256 + ((dc ^ (p & 7)) * 8) + dof];
      }
  }

  // S-phase wave mapping
  const int qt = wave >> 1, ph = wave & 1;
  const int q = qt * 16 + l16;
  const int qq = (q < 49) ? q : 48;
  const int tq = tmap(qq, gi, gj);
  const ushort_t* Mbase = Mn + (size_t)tq * MSTR + quad * 8;
  const int yq = div7(qq), xq = qq - yq * 7;
  const int fq = regof(gi * 7 + yq) * 3 + regof(gj * 7 + xq);
  const int sw = l16 & 7;

  f32x4 yac[2][4];
#pragma unroll
  for (int i = 0; i < 2; ++i)
#pragma unroll
    for (int j = 0; j < 4; ++j) yac[i][j] = (f32x4){0.f, 0.f, 0.f, 0.f};

  // prefetch head-0 B-frags
  bf16x8 bmc[8];
#pragma unroll
  for (int kk = 0; kk < 8; ++kk) bmc[kk] = *(const bf16x8*)(Mbase + kk * 32);

#pragma unroll
  for (int h = 0; h < 8; ++h) {
    // ---- S: A from Xp (swizzled), B = prefetched M regs ----
    f32x4 sacc[2];
#pragma unroll
    for (int i = 0; i < 2; ++i) sacc[i] = (f32x4){0.f, 0.f, 0.f, 0.f};
#pragma unroll
    for (int kk = 0; kk < 8; ++kk) {
#pragma unroll
      for (int i = 0; i < 2; ++i) {
        int pr = (ph * 2 + i) * 16 + l16;
        bf16x8 af = *(const bf16x8*)(&Xp[pr * 256 + (((kk * 4 + quad) ^ (pr & 7)) * 8)]);
        sacc[i] = __builtin_amdgcn_mfma_f32_16x16x32_bf16(af, bmc[kk], sacc[i], 0, 0, 0);
      }
    }
    // ---- issue next head's M loads (drain behind softmax/T/P4) ----
    bf16x8 bmn[8];
    if (h < 7) {
#pragma unroll
      for (int kk = 0; kk < 8; ++kk)
        bmn[kk] = *(const bf16x8*)(Mbase + (h + 1) * 256 + kk * 32);
    }
    // ---- bias + rel + mask -> StB[q][p] bf16 (swizzled) ----
    {
      const float aqv = aqsL[h * 64 + q];
      const float* relh = relL2 + h * 169;
#pragma unroll
      for (int i = 0; i < 2; ++i) {
        ushort4 sv;
        ushort_t* svp = &sv.x;
#pragma unroll
        for (int r = 0; r < 4; ++r) {
          int p = (ph * 2 + i) * 16 + quad * 4 + r;
          float val = -1e30f;
          if (p < 49) {
            int yp = div7(p), xp = p - yp * 7;
            int fp = regof(gi * 7 + yp) * 3 + regof(gj * 7 + xp);
            val = (sacc[i][r] + aqv + bpsL[h * 64 + p]) * 0.0625f +
                  relh[(yp - yq + 6) + 13 * (xp - xq + 6)];
            if (fp != fq) val -= 100.f;
          }
          svp[r] = f2b(val);
        }
        int lc = (ph * 2 + i) * 2 + (quad >> 1);
        *(ushort4*)(&StB[q * 64 + ((lc ^ sw) * 8) + (quad & 1) * 4]) = sv;
      }
    }
    __syncthreads();  // b1: StB scores complete

    // ---- softmax over p per row q, in-place bf16 (swizzled) ----
    {
      const int sq = tid >> 3, sub = tid & 7;
      ushort_t* row = &StB[sq * 64 + ((sub ^ (sq & 7)) * 8)];
      bf16x8 in8 = *(const bf16x8*)row;
      float v[8];
#pragma unroll
      for (int i = 0; i < 8; ++i) v[i] = b2f((ushort_t)in8[i]);
      float m = v[0];
#pragma unroll
      for (int i = 1; i < 8; ++i) m = fmaxf(m, v[i]);
      m = fmaxf(m, __shfl_xor(m, 1));
      m = fmaxf(m, __shfl_xor(m, 2));
      m = fmaxf(m, __shfl_xor(m, 4));
      float s = 0.f;
#pragma unroll
      for (int i = 0; i < 8; ++i) { v[i] = __expf(v[i] - m); s += v[i]; }
      s += __shfl_xor(s, 1);
      s += __shfl_xor(s, 2);
      s += __shfl_xor(s, 4);
      float inv = 1.f / s;
      bf16x8 w8;
#pragma unroll
      for (int i = 0; i < 8; ++i) w8[i] = (short)f2b(v[i] * inv);
      *(bf16x8*)row = w8;
    }
    __syncthreads();  // b2: wmap^T ready

    // ---- T: TT[q][d] = (X wmap)[d][q] (swizzled) ----
    {
      f32x4 tacc[2][4];
#pragma unroll
      for (int i = 0; i < 2; ++i)
#pragma unroll
        for (int j = 0; j < 4; ++j) tacc[i][j] = (f32x4){0.f, 0.f, 0.f, 0.f};
#pragma unroll
      for (int kk = 0; kk < 2; ++kk) {
        bf16x8 bw[4];
#pragma unroll
        for (int j = 0; j < 4; ++j) {
          int qr = j * 16 + l16;
          bw[j] = *(const bf16x8*)(&StB[qr * 64 + (((kk * 4 + quad) ^ sw) * 8)]);
        }
#pragma unroll
        for (int i = 0; i < 2; ++i)
#pragma unroll
          for (int j = 0; j < 4; ++j)
            tacc[i][j] = __builtin_amdgcn_mfma_f32_16x16x32_bf16(xfr[i][kk], bw[j], tacc[i][j], 0, 0, 0);
      }
#pragma unroll
      for (int i = 0; i < 2; ++i) {
        int lc = (wave * 2 + i) * 2 + (quad >> 1);
#pragma unroll
        for (int j = 0; j < 4; ++j) {
          int qr = j * 16 + l16;
          *(ushort4*)(&TT[qr * 256 + ((lc ^ sw) * 8) + (quad & 1) * 4]) =
              pack4(tacc[i][j]);
        }
      }
    }
    __syncthreads();  // b3: TT ready

    // ---- phase 4: yac[o][q] += TT . Wov_h (TT swizzled, Wov global) ----
    {
      const ushort_t* wb = Wov3 + h * 256 + quad * 8;
#pragma unroll
      for (int kk = 0; kk < 8; ++kk) {
        bf16x8 at[4];
#pragma unroll
        for (int j = 0; j < 4; ++j) {
          int qr = j * 16 + l16;
          at[j] = *(const bf16x8*)(&TT[qr * 256 + (((kk * 4 + quad) ^ sw) * 8)]);
        }
#pragma unroll
        for (int i = 0; i < 2; ++i) {
          bf16x8 bwv = *(const bf16x8*)(wb + (size_t)((wave * 2 + i) * 16 + l16) * 2048 + kk * 32);
#pragma unroll
          for (int j = 0; j < 4; ++j)
            yac[i][j] = __builtin_amdgcn_mfma_f32_16x16x32_bf16(at[j], bwv, yac[i][j], 0, 0, 0);
        }
      }
    }
    // rotate prefetch
    if (h < 7) {
#pragma unroll
      for (int kk = 0; kk < 8; ++kk) bmc[kk] = bmn[kk];
    }
  }

  // ---- epilogue: out[n][o][pos(q)] = yac + cvec ----
  float* obase = out + (size_t)n * 256 * 3136;
#pragma unroll
  for (int i = 0; i < 2; ++i) {
    const int o = (wave * 2 + i) * 16 + l16;
    const float cv = cvec[o];
#pragma unroll
    for (int j = 0; j < 4; ++j) {
#pragma unroll
      for (int r = 0; r < 4; ++r) {
        int qv = j * 16 + quad * 4 + r;
        if (qv < 49) {
          int pos = tmap(qv, gi, gj);
          obase[(size_t)o * 3136 + pos] = yac[i][j][r] + cv;
        }
      }
    }
  }
}

extern "C" void kernel_launch(void* const* d_in, const int* in_sizes, int n_in,
                              void* d_out, int out_size, void* d_ws, size_t ws_size,
                              hipStream_t stream) {
  (void)in_sizes; (void)n_in; (void)out_size; (void)ws_size;
  const float* X  = (const float*)d_in[0];
  const float* Wk = (const float*)d_in[1];
  const float* bk = (const float*)d_in[2];
  const float* Wq = (const float*)d_in[3];
  const float* bq = (const float*)d_in[4];
  const float* Wv = (const float*)d_in[5];
  const float* bv = (const float*)d_in[6];
  const float* Wo = (const float*)d_in[7];
  const float* bo = (const float*)d_in[8];
  const float* rc = (const float*)d_in[9];

  ushort_t* MT    = (ushort_t*)d_ws;                       // 8*3200*2176 u16
  ushort_t* Xroll = MT + (size_t)8 * TROWS * MSTR;         // 8*3200*256 u16
  ushort_t* Aext  = Xroll + (size_t)8 * TROWS * 256;       // 2176*256 u16
  ushort_t* Wov3  = Aext + 2176 * 256;                     // 256*2048 u16
  float* fbase = (float*)(Wov3 + 256 * 2048);
  float* cvec  = fbase;         // 256 f32
  float* relL2 = fbase + 256;   // 8*169 f32
  float* out = (float*)d_out;

  k_prep <<<dim3(1290), dim3(256), 0, stream>>>(Wk, Wq, Wo, Wv, bk, bq, bv, bo, rc,
                                                Aext, Wov3, cvec, relL2);
  k_conv <<<dim3(8 * 57), dim3(256), 0, stream>>>(X, Xroll);
  k_gemm1<<<dim3(8 * 425), dim3(256), 0, stream>>>(Xroll, Aext, MT);
  k_attn4<<<dim3(8 * 64), dim3(512), 0, stream>>>(Xroll, MT, Wov3, relL2, cvec, out);
}

// Round 10
// 319.513 us; speedup vs baseline: 1.4614x; 1.4614x over previous
//
#include <hip/hip_runtime.h>
#include <hip/hip_bf16.h>

// Swin window MHSA, MI355X, round 10: consolidation of best-measured parts.
//   k_pc   : merged prep (Aext/Wov3/cvec/relL2) + conv (X -> Xroll bf16)
//   k_gemm1: M_T[t][a'] = Xroll . Aext^T   (R5 register-staged, occ hint 2 = 73us)
//   k_attn3: fused S->softmax->T->Y per (n,window)  (R8 exact, 143us)

#define NBATCH 8
#define MSTR   2176           // M_T row stride (a'-dim)
#define TROWS  3200           // padded token rows

typedef unsigned short ushort_t;
typedef __attribute__((ext_vector_type(8))) short bf16x8;   // 8 bf16 = 4 VGPR
typedef __attribute__((ext_vector_type(8))) unsigned short u16x8;
typedef __attribute__((ext_vector_type(4))) float f32x4;    // MFMA acc

__device__ __forceinline__ float b2f(ushort_t u) {
  union { unsigned int i; float f; } v; v.i = ((unsigned int)u) << 16; return v.f;
}
__device__ __forceinline__ ushort_t f2b(float f) {
  union { float f; unsigned int u; } v; v.f = f;
  unsigned int u = v.u;
  return (ushort_t)((u + 0x7FFFu + ((u >> 16) & 1u)) >> 16);
}
__device__ __forceinline__ int regof(int y) { return (y < 49) ? 0 : ((y < 53) ? 1 : 2); }
__device__ __forceinline__ int div7(int t) { return (t * 37) >> 8; }  // t/7, t<64
__device__ __forceinline__ int tmap(int p, int gi, int gj) {
  int wi = div7(p); return (gi * 7 + wi) * 56 + gj * 7 + (p - wi * 7);
}
__device__ __forceinline__ ushort4 pack4(f32x4 a) {
  ushort4 u; u.x = f2b(a[0]); u.y = f2b(a[1]); u.z = f2b(a[2]); u.w = f2b(a[3]);
  return u;
}

// ================= merged prep + conv =================
// blocks 0..511    : Aext[h*256+a][b] = G
// blocks 512..1023 : Wov3[o][h*256+d]
// blocks 1024..1031: w1/w2 rows of Aext
// block  1032      : zero Aext rows 2064..2175
// blocks 1033..1288: cvec
// block  1289      : relL2 (+c0/16)
// blocks 1290..1745: conv (X -> Xroll), idx-1290 = n*57+y
__global__ void k_pc(const float* __restrict__ Wk, const float* __restrict__ Wq,
                     const float* __restrict__ Wo, const float* __restrict__ Wv,
                     const float* __restrict__ bk, const float* __restrict__ bq,
                     const float* __restrict__ bv, const float* __restrict__ bo,
                     const float* __restrict__ relc, const float* __restrict__ X,
                     ushort_t* __restrict__ Aext, ushort_t* __restrict__ Wov3,
                     float* __restrict__ cvec, float* __restrict__ relL2,
                     ushort_t* __restrict__ Xroll) {
  __shared__ float red[8];
  int blk = blockIdx.x, t = threadIdx.x;
  if (blk >= 1290) {
    // ---- conv ----
    const int cb = blk - 1290;
    const int n = cb / 57, y = cb % 57;
    ushort_t* xr = Xroll + (size_t)n * TROWS * 256;
    const int d = t;
    if (y == 56) {
      for (int i = d; i < 64 * 256 / 8; i += 256)
        *(u16x8*)(xr + 3136 * 256 + i * 8) = (u16x8){0,0,0,0,0,0,0,0};
      return;
    }
    const int c = d >> 4, p1 = (d >> 2) & 3, p2 = d & 3;
    const int sp = c * 16 + (((p1 + 1) & 3) << 2) + ((p2 + 1) & 3);
    const int ty = (p1 == 3) ? y : ((y == 0) ? 55 : y - 1);
    const float* rowp = X + (size_t)n * 256 * 3136 + sp * 3136 + ty * 56;
    ushort_t* orow = xr + y * 56 * 256 + d;
    for (int x = 0; x < 56; ++x) {
      int tx = (p2 == 3) ? x : ((x == 0) ? 55 : x - 1);
      orow[x * 256] = f2b(rowp[tx]);
    }
  } else if (blk < 512) {
    int h = blk >> 6, b0 = (blk & 63) << 2, a = t;
    const float* wkh = Wk + h * 65536;
    const float* wqh = Wq + h * 65536;
    float a0 = 0.f, a1 = 0.f, a2 = 0.f, a3 = 0.f;
    for (int dd = 0; dd < 256; ++dd) {
      float wk = wkh[dd * 256 + a];
      float4 w4 = *(const float4*)(wqh + dd * 256 + b0);
      a0 += wk * w4.x; a1 += wk * w4.y; a2 += wk * w4.z; a3 += wk * w4.w;
    }
    ushort4 u; u.x = f2b(a0); u.y = f2b(a1); u.z = f2b(a2); u.w = f2b(a3);
    *(ushort4*)(Aext + (h * 256 + a) * 256 + b0) = u;
  } else if (blk < 1024) {
    int bb = blk - 512;
    int h = bb >> 6, o0 = (bb & 63) << 2, d = t;
    float a0 = 0.f, a1 = 0.f, a2 = 0.f, a3 = 0.f;
    for (int dd = 0; dd < 256; ++dd) {
      float wv = Wv[(h * 256 + dd) * 256 + d];
      a0 += Wo[(o0 + 0) * 2048 + h * 256 + dd] * wv;
      a1 += Wo[(o0 + 1) * 2048 + h * 256 + dd] * wv;
      a2 += Wo[(o0 + 2) * 2048 + h * 256 + dd] * wv;
      a3 += Wo[(o0 + 3) * 2048 + h * 256 + dd] * wv;
    }
    Wov3[(o0 + 0) * 2048 + h * 256 + d] = f2b(a0);
    Wov3[(o0 + 1) * 2048 + h * 256 + d] = f2b(a1);
    Wov3[(o0 + 2) * 2048 + h * 256 + d] = f2b(a2);
    Wov3[(o0 + 3) * 2048 + h * 256 + d] = f2b(a3);
  } else if (blk < 1032) {
    int h = blk - 1024;
    float s1 = 0.f, s2 = 0.f;
    for (int dd = 0; dd < 256; ++dd) {
      s1 += bk[h * 256 + dd] * Wq[(h * 256 + dd) * 256 + t];
      s2 += bq[h * 256 + dd] * Wk[(h * 256 + dd) * 256 + t];
    }
    Aext[(2048 + h) * 256 + t] = f2b(s1);
    Aext[(2056 + h) * 256 + t] = f2b(s2);
  } else if (blk == 1032) {
    for (int i = t; i < 112 * 256 / 8; i += 256)
      *(u16x8*)(Aext + 2064 * 256 + i * 8) = (u16x8){0,0,0,0,0,0,0,0};
  } else if (blk < 1289) {
    int o = blk - 1033;
    const float* wob = Wo + o * 2048;
    float acc = 0.f;
#pragma unroll
    for (int j = 0; j < 8; ++j) acc += wob[j * 256 + t] * bv[j * 256 + t];
#pragma unroll
    for (int s = 1; s < 64; s <<= 1) acc += __shfl_xor(acc, s);
    if ((t & 63) == 0) red[t >> 6] = acc;
    __syncthreads();
    if (t == 0) cvec[o] = bo[o] + red[0] + red[1] + red[2] + red[3];
  } else {
    if (t < 8) {
      float c = 0.f;
      for (int dd = 0; dd < 256; ++dd) c += bk[t * 256 + dd] * bq[t * 256 + dd];
      red[t] = c * 0.0625f;
    }
    __syncthreads();
    for (int i = t; i < 8 * 169; i += 256) {
      int h = i / 169, idx = i - h * 169;
      relL2[i] = relc[idx * 8 + h] + red[h];
    }
  }
}

// ================= gemm1: R5 exact (register-staged, occ hint 2) ==========
__global__ __launch_bounds__(256, 2) void k_gemm1(
    const ushort_t* __restrict__ Xroll, const ushort_t* __restrict__ Aext,
    ushort_t* __restrict__ MT) {
  __shared__ ushort_t Asm[128 * 72];
  __shared__ ushort_t Bsm[128 * 72];
  const int bx = blockIdx.x;
  const int n = bx / 425, r = bx % 425;
  const int tt = r / 17, aa = r % 17;
  const int a0 = aa * 128, t0 = tt * 128;
  const int tid = threadIdx.x, wave = tid >> 6, lane = tid & 63;
  const int quad = lane >> 4, l16 = lane & 15;
  const int wa = wave >> 1, wt = wave & 1;
  const ushort_t* Xn = Xroll + (size_t)n * TROWS * 256;
  ushort_t* Mn = MT + (size_t)n * TROWS * MSTR;

  const int sr = tid >> 1, sc = (tid & 1) * 4;
  bf16x8 ra[4], rb[4];
#pragma unroll
  for (int i = 0; i < 4; ++i) {
    ra[i] = *(const bf16x8*)(Aext + (a0 + sr) * 256 + (sc + i) * 8);
    rb[i] = *(const bf16x8*)(Xn + (t0 + sr) * 256 + (sc + i) * 8);
  }

  f32x4 acc[4][4];
#pragma unroll
  for (int i = 0; i < 4; ++i)
#pragma unroll
    for (int j = 0; j < 4; ++j) acc[i][j] = (f32x4){0.f, 0.f, 0.f, 0.f};

  for (int kit = 0; kit < 4; ++kit) {
#pragma unroll
    for (int i = 0; i < 4; ++i) {
      *(bf16x8*)(&Asm[sr * 72 + (sc + i) * 8]) = ra[i];
      *(bf16x8*)(&Bsm[sr * 72 + (sc + i) * 8]) = rb[i];
    }
    __syncthreads();
    if (kit < 3) {
      int k0 = (kit + 1) * 64;
#pragma unroll
      for (int i = 0; i < 4; ++i) {
        ra[i] = *(const bf16x8*)(Aext + (a0 + sr) * 256 + k0 + (sc + i) * 8);
        rb[i] = *(const bf16x8*)(Xn + (t0 + sr) * 256 + k0 + (sc + i) * 8);
      }
    }
#pragma unroll
    for (int kk = 0; kk < 2; ++kk) {
      bf16x8 af[4], bf[4];
#pragma unroll
      for (int i = 0; i < 4; ++i)
        af[i] = *(const bf16x8*)(&Asm[(wa * 64 + i * 16 + l16) * 72 + kk * 32 + quad * 8]);
#pragma unroll
      for (int j = 0; j < 4; ++j)
        bf[j] = *(const bf16x8*)(&Bsm[(wt * 64 + j * 16 + l16) * 72 + kk * 32 + quad * 8]);
#pragma unroll
      for (int i = 0; i < 4; ++i)
#pragma unroll
        for (int j = 0; j < 4; ++j)
          acc[i][j] = __builtin_amdgcn_mfma_f32_16x16x32_bf16(af[i], bf[j], acc[i][j], 0, 0, 0);
    }
    __syncthreads();
  }
#pragma unroll
  for (int i = 0; i < 4; ++i)
#pragma unroll
    for (int j = 0; j < 4; ++j) {
      int tg = t0 + wt * 64 + j * 16 + l16;
      int ag = a0 + wa * 64 + i * 16 + quad * 4;
      *(ushort4*)(Mn + (size_t)tg * MSTR + ag) = pack4(acc[i][j]);
    }
}

// ================= attn3 (R8 exact) =================
#define XP3 264
__global__ __launch_bounds__(512, 4) void k_attn3(
    const ushort_t* __restrict__ Xroll, const ushort_t* __restrict__ MT,
    const ushort_t* __restrict__ Wov3, const float* __restrict__ relL2,
    const float* __restrict__ cvec, float* __restrict__ out) {
  __shared__ ushort_t Xp[64 * XP3];
  __shared__ ushort_t TT[64 * XP3];
  __shared__ ushort_t StB[64 * 72];
  __shared__ float aqsL[8 * 64];
  __shared__ float bpsL[8 * 64];

  const int tid = threadIdx.x;
  const int wave = tid >> 6, lane = tid & 63;
  const int quad = lane >> 4, l16 = lane & 15;
  const int n = blockIdx.x >> 6, g = blockIdx.x & 63;
  const int gi = g >> 3, gj = g & 7;
  const ushort_t* Xn = Xroll + (size_t)n * TROWS * 256;
  const ushort_t* Mn = MT + (size_t)n * TROWS * MSTR;

  {
    const int p = tid & 63, cg = tid >> 6;
    if (p < 49) {
      int t = tmap(p, gi, gj);
#pragma unroll
      for (int i = 0; i < 4; ++i)
        *(u16x8*)(&Xp[p * XP3 + (cg * 4 + i) * 8]) =
            *(const u16x8*)(Xn + t * 256 + (cg * 4 + i) * 8);
    } else {
#pragma unroll
      for (int i = 0; i < 4; ++i)
        *(u16x8*)(&Xp[p * XP3 + (cg * 4 + i) * 8]) = (u16x8){0,0,0,0,0,0,0,0};
    }
  }
  {
    const int h = tid >> 6, q = tid & 63;
    int qq = (q < 49) ? q : 48;
    int t = tmap(qq, gi, gj);
    aqsL[h * 64 + q] = b2f(Mn[(size_t)t * MSTR + 2048 + h]);
    bpsL[h * 64 + q] = b2f(Mn[(size_t)t * MSTR + 2056 + h]);
  }
  __syncthreads();

  bf16x8 xfr[2][2];
#pragma unroll
  for (int i = 0; i < 2; ++i) {
    const int d = (wave * 2 + i) * 16 + l16;
#pragma unroll
    for (int kk = 0; kk < 2; ++kk)
#pragma unroll
      for (int j = 0; j < 8; ++j)
        xfr[i][kk][j] = (short)Xp[(kk * 32 + quad * 8 + j) * XP3 + d];
  }

  const int qt = wave >> 1, ph = wave & 1;
  const int q = qt * 16 + l16;
  const int qq = (q < 49) ? q : 48;
  const int tq = tmap(qq, gi, gj);
  const ushort_t* Mbase = Mn + (size_t)tq * MSTR + quad * 8;
  const int yq = div7(qq), xq = qq - yq * 7;
  const int fq = regof(gi * 7 + yq) * 3 + regof(gj * 7 + xq);

  f32x4 yac[2][4];
#pragma unroll
  for (int i = 0; i < 2; ++i)
#pragma unroll
    for (int j = 0; j < 4; ++j) yac[i][j] = (f32x4){0.f, 0.f, 0.f, 0.f};

  for (int h = 0; h < 8; ++h) {
    f32x4 sacc[2];
#pragma unroll
    for (int i = 0; i < 2; ++i) sacc[i] = (f32x4){0.f, 0.f, 0.f, 0.f};
    const ushort_t* mrow = Mbase + h * 256;
#pragma unroll
    for (int kk = 0; kk < 8; ++kk) {
      bf16x8 bm = *(const bf16x8*)(mrow + kk * 32);
#pragma unroll
      for (int i = 0; i < 2; ++i) {
        bf16x8 af = *(const bf16x8*)(&Xp[((ph * 2 + i) * 16 + l16) * XP3 + kk * 32 + quad * 8]);
        sacc[i] = __builtin_amdgcn_mfma_f32_16x16x32_bf16(af, bm, sacc[i], 0, 0, 0);
      }
    }
    {
      const float aqv = aqsL[h * 64 + q];
      const float* relh = relL2 + h * 169;
#pragma unroll
      for (int i = 0; i < 2; ++i) {
        ushort4 sv;
        ushort_t* svp = &sv.x;
#pragma unroll
        for (int r = 0; r < 4; ++r) {
          int p = (ph * 2 + i) * 16 + quad * 4 + r;
          float val = -1e30f;
          if (p < 49) {
            int yp = div7(p), xp = p - yp * 7;
            int fp = regof(gi * 7 + yp) * 3 + regof(gj * 7 + xp);
            val = (sacc[i][r] + aqv + bpsL[h * 64 + p]) * 0.0625f +
                  relh[(yp - yq + 6) + 13 * (xp - xq + 6)];
            if (fp != fq) val -= 100.f;
          }
          svp[r] = f2b(val);
        }
        *(ushort4*)(&StB[q * 72 + (ph * 2 + i) * 16 + quad * 4]) = sv;
      }
    }
    __syncthreads();  // b1: StB scores complete

    {
      const int sq = tid >> 3, sub = tid & 7;
      ushort_t* row = &StB[sq * 72 + sub * 8];
      bf16x8 in8 = *(const bf16x8*)row;
      float v[8];
#pragma unroll
      for (int i = 0; i < 8; ++i) v[i] = b2f((ushort_t)in8[i]);
      float m = v[0];
#pragma unroll
      for (int i = 1; i < 8; ++i) m = fmaxf(m, v[i]);
      m = fmaxf(m, __shfl_xor(m, 1));
      m = fmaxf(m, __shfl_xor(m, 2));
      m = fmaxf(m, __shfl_xor(m, 4));
      float s = 0.f;
#pragma unroll
      for (int i = 0; i < 8; ++i) { v[i] = __expf(v[i] - m); s += v[i]; }
      s += __shfl_xor(s, 1);
      s += __shfl_xor(s, 2);
      s += __shfl_xor(s, 4);
      float inv = 1.f / s;
      bf16x8 w8;
#pragma unroll
      for (int i = 0; i < 8; ++i) w8[i] = (short)f2b(v[i] * inv);
      *(bf16x8*)row = w8;
    }
    __syncthreads();  // b2: wmap^T ready

    {
      f32x4 tacc[2][4];
#pragma unroll
      for (int i = 0; i < 2; ++i)
#pragma unroll
        for (int j = 0; j < 4; ++j) tacc[i][j] = (f32x4){0.f, 0.f, 0.f, 0.f};
#pragma unroll
      for (int kk = 0; kk < 2; ++kk) {
        bf16x8 bw[4];
#pragma unroll
        for (int j = 0; j < 4; ++j)
          bw[j] = *(const bf16x8*)(&StB[(j * 16 + l16) * 72 + kk * 32 + quad * 8]);
#pragma unroll
        for (int i = 0; i < 2; ++i)
#pragma unroll
          for (int j = 0; j < 4; ++j)
            tacc[i][j] = __builtin_amdgcn_mfma_f32_16x16x32_bf16(xfr[i][kk], bw[j], tacc[i][j], 0, 0, 0);
      }
#pragma unroll
      for (int i = 0; i < 2; ++i)
#pragma unroll
        for (int j = 0; j < 4; ++j)
          *(ushort4*)(&TT[(j * 16 + l16) * XP3 + (wave * 2 + i) * 16 + quad * 4]) =
              pack4(tacc[i][j]);
    }
    __syncthreads();  // b3: TT ready

    {
      const ushort_t* wb = Wov3 + h * 256 + quad * 8;
#pragma unroll
      for (int kk = 0; kk < 8; ++kk) {
        bf16x8 at[4];
#pragma unroll
        for (int j = 0; j < 4; ++j)
          at[j] = *(const bf16x8*)(&TT[(j * 16 + l16) * XP3 + kk * 32 + quad * 8]);
#pragma unroll
        for (int i = 0; i < 2; ++i) {
          bf16x8 bwv = *(const bf16x8*)(wb + (size_t)((wave * 2 + i) * 16 + l16) * 2048 + kk * 32);
#pragma unroll
          for (int j = 0; j < 4; ++j)
            yac[i][j] = __builtin_amdgcn_mfma_f32_16x16x32_bf16(at[j], bwv, yac[i][j], 0, 0, 0);
        }
      }
    }
  }

  float* obase = out + (size_t)n * 256 * 3136;
#pragma unroll
  for (int i = 0; i < 2; ++i) {
    const int o = (wave * 2 + i) * 16 + l16;
    const float cv = cvec[o];
#pragma unroll
    for (int j = 0; j < 4; ++j) {
#pragma unroll
      for (int r = 0; r < 4; ++r) {
        int qv = j * 16 + quad * 4 + r;
        if (qv < 49) {
          int pos = tmap(qv, gi, gj);
          obase[(size_t)o * 3136 + pos] = yac[i][j][r] + cv;
        }
      }
    }
  }
}

extern "C" void kernel_launch(void* const* d_in, const int* in_sizes, int n_in,
                              void* d_out, int out_size, void* d_ws, size_t ws_size,
                              hipStream_t stream) {
  (void)in_sizes; (void)n_in; (void)out_size; (void)ws_size;
  const float* X  = (const float*)d_in[0];
  const float* Wk = (const float*)d_in[1];
  const float* bk = (const float*)d_in[2];
  const float* Wq = (const float*)d_in[3];
  const float* bq = (const float*)d_in[4];
  const float* Wv = (const float*)d_in[5];
  const float* bv = (const float*)d_in[6];
  const float* Wo = (const float*)d_in[7];
  const float* bo = (const float*)d_in[8];
  const float* rc = (const float*)d_in[9];

  ushort_t* MT    = (ushort_t*)d_ws;                       // 8*3200*2176 u16
  ushort_t* Xroll = MT + (size_t)8 * TROWS * MSTR;         // 8*3200*256 u16
  ushort_t* Aext  = Xroll + (size_t)8 * TROWS * 256;       // 2176*256 u16
  ushort_t* Wov3  = Aext + 2176 * 256;                     // 256*2048 u16
  float* fbase = (float*)(Wov3 + 256 * 2048);
  float* cvec  = fbase;         // 256 f32
  float* relL2 = fbase + 256;   // 8*169 f32
  float* out = (float*)d_out;

  k_pc   <<<dim3(1746), dim3(256), 0, stream>>>(Wk, Wq, Wo, Wv, bk, bq, bv, bo, rc, X,
                                                Aext, Wov3, cvec, relL2, Xroll);
  k_gemm1<<<dim3(8 * 425), dim3(256), 0, stream>>>(Xroll, Aext, MT);
  k_attn3<<<dim3(8 * 64), dim3(512), 0, stream>>>(Xroll, MT, Wov3, relL2, cvec, out);
}